// Round 1
// baseline (425.824 us; speedup 1.0000x reference)
//
#include <hip/hip_runtime.h>
#include <math.h>

// EquivariantWSSHead: V=100000 vertices, E=1600000 edges, C0=C1=16.
//
// Per-edge math factors through per-source-vertex dot products:
//   u1·w = cg*(a·w) - sg*(b·w),  u2·w = sg*(a·w) + cg*(b·w)
// so we precompute a 16-float (64 B) table per vertex, gather one cache
// line per edge, and scatter 4 float atomics per edge onto dst.
//
// ws layout: acc[V*4] (m0,mv1,mv2,deg) | table[V*16] | selfbuf[V*4]

#define THREADS 256

__global__ void precompute_kernel(const float* __restrict__ x,
                                  const float* __restrict__ w_self0,
                                  const float* __restrict__ w_n00,
                                  const float* __restrict__ w_n10,
                                  const float* __restrict__ w_self11,
                                  const float* __restrict__ w_n01,
                                  const float* __restrict__ w_n11,
                                  float* __restrict__ table,
                                  float* __restrict__ selfbuf,
                                  int V) {
    int v = blockIdx.x * blockDim.x + threadIdx.x;
    if (v >= V) return;
    const float* xr = x + (size_t)v * 48;
    float x0[16], a[16], b[16];
#pragma unroll
    for (int i = 0; i < 16; ++i) x0[i] = xr[i];
#pragma unroll
    for (int i = 0; i < 16; ++i) { a[i] = xr[16 + 2 * i]; b[i] = xr[17 + 2 * i]; }

    float d00 = 0.f, aw0 = 0.f, bw0 = 0.f, aw1 = 0.f, bw1 = 0.f;
    float d01a = 0.f, d01b = 0.f;
    float aP = 0.f, bP = 0.f, aQ = 0.f, bQ = 0.f;
    float aR = 0.f, bR = 0.f, aS = 0.f, bS = 0.f;
    float selfmag = 0.f, t1s = 0.f, t2s = 0.f;
#pragma unroll
    for (int i = 0; i < 16; ++i) {
        d00     += x0[i] * w_n00[i];
        selfmag += x0[i] * w_self0[i];
        d01a    += x0[i] * w_n01[i * 2 + 0];
        d01b    += x0[i] * w_n01[i * 2 + 1];
        float w0 = w_n10[i * 2 + 0], w1 = w_n10[i * 2 + 1];
        aw0 += a[i] * w0;  bw0 += b[i] * w0;
        aw1 += a[i] * w1;  bw1 += b[i] * w1;
        float p = w_n11[i * 4 + 0], q = w_n11[i * 4 + 1];
        float r = w_n11[i * 4 + 2], s = w_n11[i * 4 + 3];
        aP += a[i] * p;  bP += b[i] * p;
        aQ += a[i] * q;  bQ += b[i] * q;
        aR += a[i] * r;  bR += b[i] * r;
        aS += a[i] * s;  bS += b[i] * s;
        float sa_ = w_self11[i * 2 + 0], sb_ = w_self11[i * 2 + 1];
        t1s += a[i] * sa_ - b[i] * sb_;
        t2s += b[i] * sa_ + a[i] * sb_;
    }
    float* t = table + (size_t)v * 16;
    t[0] = d00;  t[1] = aw0;  t[2] = bw0;  t[3] = aw1;
    t[4] = bw1;  t[5] = d01a; t[6] = d01b; t[7] = aP;
    t[8] = bP;   t[9] = aQ;   t[10] = bQ;  t[11] = aR;
    t[12] = bR;  t[13] = aS;  t[14] = bS;  t[15] = 0.f;
    float* sf = selfbuf + (size_t)v * 4;
    sf[0] = selfmag; sf[1] = t1s; sf[2] = t2s; sf[3] = 0.f;
}

__global__ void edge_kernel(const int* __restrict__ src,
                            const int* __restrict__ dst,
                            const float* __restrict__ angles,
                            const float* __restrict__ transporters,
                            const float* __restrict__ table,
                            float* __restrict__ acc,
                            int E) {
    int e = blockIdx.x * blockDim.x + threadIdx.x;
    if (e >= E) return;
    int s = src[e];
    int d = dst[e];
    float ang = angles[e], tr = transporters[e];
    float st, ct, sg, cg;
    sincosf(ang, &st, &ct);
    sincosf(tr, &sg, &cg);
    float c2t = ct * ct - st * st;
    float s2t = 2.0f * st * ct;

    const float4* tp = (const float4*)(table + (size_t)s * 16);
    float4 T0 = tp[0], T1 = tp[1], T2 = tp[2], T3 = tp[3];
    float d00 = T0.x, aw0 = T0.y, bw0 = T0.z, aw1 = T0.w;
    float bw1 = T1.x, d01a = T1.y, d01b = T1.z, aP = T1.w;
    float bP = T2.x, aQ = T2.y, bQ = T2.z, aR = T2.w;
    float bR = T3.x, aS = T3.y, bS = T3.z;

    // u1·w = cg*aw - sg*bw ; u2·w = sg*aw + cg*bw
    float u1w0 = cg * aw0 - sg * bw0, u2w0 = sg * aw0 + cg * bw0;
    float u1w1 = cg * aw1 - sg * bw1, u2w1 = sg * aw1 + cg * bw1;
    float m0 = d00 + ct * u1w0 + st * u2w0 - st * u1w1 + ct * u2w1;

    float u1p = cg * aP - sg * bP, u2p = sg * aP + cg * bP;
    float u1q = cg * aQ - sg * bQ, u2q = sg * aQ + cg * bQ;
    float u1r = cg * aR - sg * bR, u2r = sg * aR + cg * bR;
    float u1s = cg * aS - sg * bS, u2s = sg * aS + cg * bS;

    float mv1 = d01a * ct - d01b * st
              + u1p - u2q
              + c2t * u1r + s2t * u2r   // r1·r
              - (s2t * u1s - c2t * u2s); // -r2·s
    float mv2 = d01a * st + d01b * ct
              + u2p + u1q
              + s2t * u1r - c2t * u2r   // r2·r
              + c2t * u1s + s2t * u2s;  // r1·s

    float* ap = acc + (size_t)d * 4;
    atomicAdd(ap + 0, m0);
    atomicAdd(ap + 1, mv1);
    atomicAdd(ap + 2, mv2);
    atomicAdd(ap + 3, 1.0f);
}

__global__ void finalize_kernel(const float4* __restrict__ acc,
                                const float* __restrict__ selfbuf,
                                const float* __restrict__ e1,
                                const float* __restrict__ e2,
                                float* __restrict__ out,
                                int V) {
    int v = blockIdx.x * blockDim.x + threadIdx.x;
    if (v >= V) return;
    float4 a = acc[v];
    float inv = 1.0f / fmaxf(a.w, 1.0f);
    const float* sf = selfbuf + (size_t)v * 4;
    float mag = a.x * inv + sf[0];
    float t1  = a.y * inv + sf[1];
    float t2  = a.z * inv + sf[2];
    float scale = 2.0f / (1.0f + expf(-mag));
    float e1x = e1[v * 3 + 0], e1y = e1[v * 3 + 1], e1z = e1[v * 3 + 2];
    float e2x = e2[v * 3 + 0], e2y = e2[v * 3 + 1], e2z = e2[v * 3 + 2];
    out[v * 3 + 0] = (t1 * e1x + t2 * e2x) * scale;
    out[v * 3 + 1] = (t1 * e1y + t2 * e2y) * scale;
    out[v * 3 + 2] = (t1 * e1z + t2 * e2z) * scale;
}

extern "C" void kernel_launch(void* const* d_in, const int* in_sizes, int n_in,
                              void* d_out, int out_size, void* d_ws, size_t ws_size,
                              hipStream_t stream) {
    const float* x            = (const float*)d_in[0];
    const int*   edge_index   = (const int*)d_in[1];   // harness contract: int32
    const float* angles       = (const float*)d_in[2];
    const float* transporters = (const float*)d_in[3];
    const float* e1           = (const float*)d_in[4];
    const float* e2           = (const float*)d_in[5];
    const float* w_self0      = (const float*)d_in[6];
    const float* w_n00        = (const float*)d_in[7];
    const float* w_n10        = (const float*)d_in[8];
    const float* w_self11     = (const float*)d_in[9];
    const float* w_n01        = (const float*)d_in[10];
    const float* w_n11        = (const float*)d_in[11];
    float* out = (float*)d_out;

    int V = in_sizes[0] / 48;
    int E = in_sizes[2];
    const int* src = edge_index;
    const int* dst = edge_index + E;

    float* acc     = (float*)d_ws;              // V*4 floats
    float* table   = acc + (size_t)V * 4;       // V*16 floats
    float* selfbuf = table + (size_t)V * 16;    // V*4 floats

    hipMemsetAsync(acc, 0, (size_t)V * 4 * sizeof(float), stream);

    int gv = (V + THREADS - 1) / THREADS;
    int ge = (E + THREADS - 1) / THREADS;
    precompute_kernel<<<gv, THREADS, 0, stream>>>(x, w_self0, w_n00, w_n10,
                                                  w_self11, w_n01, w_n11,
                                                  table, selfbuf, V);
    edge_kernel<<<ge, THREADS, 0, stream>>>(src, dst, angles, transporters,
                                            table, acc, E);
    finalize_kernel<<<gv, THREADS, 0, stream>>>((const float4*)acc, selfbuf,
                                                e1, e2, out, V);
}

// Round 2
// 262.534 us; speedup vs baseline: 1.6220x; 1.6220x over previous
//
#include <hip/hip_runtime.h>
#include <math.h>

// EquivariantWSSHead: V=100000 vertices, E=1600000 edges, C0=C1=16.
//
// R1 finding: device-scope fp atomics write through TCC at 32 B/atomic
// (WRITE_SIZE == 6.4M x 32B exactly); edge kernel was atomic-bound at
// ~20 G atomics/s. R2: replace 4 fp atomics/edge with 1 int atomic/edge:
//   K2 histogram: rank[e] = atomicAdd(count[dst], 1)
//   K3 alloc:     per-vertex segment base via wave-aggregated atomic
//   K4 edge:      compute message, scatter float4 to msg[off[dst]+rank]
//   K5 reduce:    per-vertex sequential segment sum + finalize
//
// Per-edge math factors through per-source-vertex dot products:
//   u1·w = cg*(a·w) - sg*(b·w),  u2·w = sg*(a·w) + cg*(b·w)
// so K1 precomputes a 16-float (64 B) table per vertex; each edge
// gathers exactly one cache line.

#define THREADS 256

__global__ void precompute_kernel(const float* __restrict__ x,
                                  const float* __restrict__ w_self0,
                                  const float* __restrict__ w_n00,
                                  const float* __restrict__ w_n10,
                                  const float* __restrict__ w_self11,
                                  const float* __restrict__ w_n01,
                                  const float* __restrict__ w_n11,
                                  float* __restrict__ table,
                                  float* __restrict__ selfbuf,
                                  int V) {
    int v = blockIdx.x * blockDim.x + threadIdx.x;
    if (v >= V) return;
    const float* xr = x + (size_t)v * 48;
    float x0[16], a[16], b[16];
#pragma unroll
    for (int i = 0; i < 16; ++i) x0[i] = xr[i];
#pragma unroll
    for (int i = 0; i < 16; ++i) { a[i] = xr[16 + 2 * i]; b[i] = xr[17 + 2 * i]; }

    float d00 = 0.f, aw0 = 0.f, bw0 = 0.f, aw1 = 0.f, bw1 = 0.f;
    float d01a = 0.f, d01b = 0.f;
    float aP = 0.f, bP = 0.f, aQ = 0.f, bQ = 0.f;
    float aR = 0.f, bR = 0.f, aS = 0.f, bS = 0.f;
    float selfmag = 0.f, t1s = 0.f, t2s = 0.f;
#pragma unroll
    for (int i = 0; i < 16; ++i) {
        d00     += x0[i] * w_n00[i];
        selfmag += x0[i] * w_self0[i];
        d01a    += x0[i] * w_n01[i * 2 + 0];
        d01b    += x0[i] * w_n01[i * 2 + 1];
        float w0 = w_n10[i * 2 + 0], w1 = w_n10[i * 2 + 1];
        aw0 += a[i] * w0;  bw0 += b[i] * w0;
        aw1 += a[i] * w1;  bw1 += b[i] * w1;
        float p = w_n11[i * 4 + 0], q = w_n11[i * 4 + 1];
        float r = w_n11[i * 4 + 2], s = w_n11[i * 4 + 3];
        aP += a[i] * p;  bP += b[i] * p;
        aQ += a[i] * q;  bQ += b[i] * q;
        aR += a[i] * r;  bR += b[i] * r;
        aS += a[i] * s;  bS += b[i] * s;
        float sa_ = w_self11[i * 2 + 0], sb_ = w_self11[i * 2 + 1];
        t1s += a[i] * sa_ - b[i] * sb_;
        t2s += b[i] * sa_ + a[i] * sb_;
    }
    float* t = table + (size_t)v * 16;
    t[0] = d00;  t[1] = aw0;  t[2] = bw0;  t[3] = aw1;
    t[4] = bw1;  t[5] = d01a; t[6] = d01b; t[7] = aP;
    t[8] = bP;   t[9] = aQ;   t[10] = bQ;  t[11] = aR;
    t[12] = bR;  t[13] = aS;  t[14] = bS;  t[15] = 0.f;
    float* sf = selfbuf + (size_t)v * 4;
    sf[0] = selfmag; sf[1] = t1s; sf[2] = t2s; sf[3] = 0.f;
}

// K2: per-edge rank within its dst bucket + per-dst count.
__global__ void histogram_kernel(const int* __restrict__ dst,
                                 int* __restrict__ count,
                                 int* __restrict__ rank,
                                 int E) {
    int e = blockIdx.x * blockDim.x + threadIdx.x;
    if (e >= E) return;
    rank[e] = atomicAdd(&count[dst[e]], 1);
}

// K3: contiguous segment base per vertex. Segment ORDER is irrelevant, so
// instead of a full prefix scan we wave-aggregate: in-wave shfl prefix sum,
// one atomicAdd(cursor, waveTotal) per wave (~1.6K atomics total).
__global__ void alloc_kernel(const int* __restrict__ count,
                             int* __restrict__ off,
                             int* __restrict__ cursor,
                             int V) {
    int v = blockIdx.x * blockDim.x + threadIdx.x;
    int c = (v < V) ? count[v] : 0;
    int lane = threadIdx.x & 63;
    int incl = c;
#pragma unroll
    for (int d = 1; d < 64; d <<= 1) {
        int n = __shfl_up(incl, d);
        if (lane >= d) incl += n;
    }
    int base = 0;
    if (lane == 63) base = atomicAdd(cursor, incl);
    base = __shfl(base, 63);
    if (v < V) off[v] = base + incl - c;
}

// K4: compute per-edge message, scatter into contiguous per-dst segment.
__global__ void edge_kernel(const int* __restrict__ src,
                            const int* __restrict__ dst,
                            const float* __restrict__ angles,
                            const float* __restrict__ transporters,
                            const float* __restrict__ table,
                            const int* __restrict__ off,
                            const int* __restrict__ rank,
                            float4* __restrict__ msg,
                            int E) {
    int e = blockIdx.x * blockDim.x + threadIdx.x;
    if (e >= E) return;
    int s = src[e];
    int d = dst[e];
    float ang = angles[e], tr = transporters[e];
    float st, ct, sg, cg;
    sincosf(ang, &st, &ct);
    sincosf(tr, &sg, &cg);
    float c2t = ct * ct - st * st;
    float s2t = 2.0f * st * ct;

    const float4* tp = (const float4*)(table + (size_t)s * 16);
    float4 T0 = tp[0], T1 = tp[1], T2 = tp[2], T3 = tp[3];
    float d00 = T0.x, aw0 = T0.y, bw0 = T0.z, aw1 = T0.w;
    float bw1 = T1.x, d01a = T1.y, d01b = T1.z, aP = T1.w;
    float bP = T2.x, aQ = T2.y, bQ = T2.z, aR = T2.w;
    float bR = T3.x, aS = T3.y, bS = T3.z;

    float u1w0 = cg * aw0 - sg * bw0, u2w0 = sg * aw0 + cg * bw0;
    float u1w1 = cg * aw1 - sg * bw1, u2w1 = sg * aw1 + cg * bw1;
    float m0 = d00 + ct * u1w0 + st * u2w0 - st * u1w1 + ct * u2w1;

    float u1p = cg * aP - sg * bP, u2p = sg * aP + cg * bP;
    float u1q = cg * aQ - sg * bQ, u2q = sg * aQ + cg * bQ;
    float u1r = cg * aR - sg * bR, u2r = sg * aR + cg * bR;
    float u1s = cg * aS - sg * bS, u2s = sg * aS + cg * bS;

    float mv1 = d01a * ct - d01b * st
              + u1p - u2q
              + c2t * u1r + s2t * u2r
              - (s2t * u1s - c2t * u2s);
    float mv2 = d01a * st + d01b * ct
              + u2p + u1q
              + s2t * u1r - c2t * u2r
              + c2t * u1s + s2t * u2s;

    int pos = off[d] + rank[e];
    msg[pos] = make_float4(m0, mv1, mv2, 0.0f);
}

// K5: per-vertex segment reduction + finalize.
__global__ void reduce_finalize_kernel(const float4* __restrict__ msg,
                                       const int* __restrict__ off,
                                       const int* __restrict__ count,
                                       const float* __restrict__ selfbuf,
                                       const float* __restrict__ e1,
                                       const float* __restrict__ e2,
                                       float* __restrict__ out,
                                       int V) {
    int v = blockIdx.x * blockDim.x + threadIdx.x;
    if (v >= V) return;
    int o = off[v];
    int n = count[v];
    float m0 = 0.f, a1 = 0.f, a2 = 0.f;
    for (int i = 0; i < n; ++i) {
        float4 m = msg[o + i];
        m0 += m.x; a1 += m.y; a2 += m.z;
    }
    float inv = 1.0f / fmaxf((float)n, 1.0f);
    const float* sf = selfbuf + (size_t)v * 4;
    float mag = m0 * inv + sf[0];
    float t1  = a1 * inv + sf[1];
    float t2  = a2 * inv + sf[2];
    float scale = 2.0f / (1.0f + expf(-mag));
    float e1x = e1[v * 3 + 0], e1y = e1[v * 3 + 1], e1z = e1[v * 3 + 2];
    float e2x = e2[v * 3 + 0], e2y = e2[v * 3 + 1], e2z = e2[v * 3 + 2];
    out[v * 3 + 0] = (t1 * e1x + t2 * e2x) * scale;
    out[v * 3 + 1] = (t1 * e1y + t2 * e2y) * scale;
    out[v * 3 + 2] = (t1 * e1z + t2 * e2z) * scale;
}

extern "C" void kernel_launch(void* const* d_in, const int* in_sizes, int n_in,
                              void* d_out, int out_size, void* d_ws, size_t ws_size,
                              hipStream_t stream) {
    const float* x            = (const float*)d_in[0];
    const int*   edge_index   = (const int*)d_in[1];
    const float* angles       = (const float*)d_in[2];
    const float* transporters = (const float*)d_in[3];
    const float* e1           = (const float*)d_in[4];
    const float* e2           = (const float*)d_in[5];
    const float* w_self0      = (const float*)d_in[6];
    const float* w_n00        = (const float*)d_in[7];
    const float* w_n10        = (const float*)d_in[8];
    const float* w_self11     = (const float*)d_in[9];
    const float* w_n01        = (const float*)d_in[10];
    const float* w_n11        = (const float*)d_in[11];
    float* out = (float*)d_out;

    int V = in_sizes[0] / 48;
    int E = in_sizes[2];
    const int* src = edge_index;
    const int* dst = edge_index + E;

    // ws layout (16B-aligned sections):
    char* p = (char*)d_ws;
    auto align16 = [](char* q) {
        return (char*)(((uintptr_t)q + 15) & ~(uintptr_t)15);
    };
    int* count  = (int*)p;             p += (size_t)V * 4;        // zeroed
    int* cursor = (int*)p;             p += 16;                   // zeroed
    int* off    = (int*)p;             p += (size_t)V * 4;
    int* rank   = (int*)p;             p += (size_t)E * 4;
    p = align16(p);
    float* table   = (float*)p;        p += (size_t)V * 16 * 4;
    float* selfbuf = (float*)p;        p += (size_t)V * 4 * 4;
    p = align16(p);
    float4* msg    = (float4*)p;       // E * 16 bytes

    // zero count + cursor (contiguous)
    hipMemsetAsync(count, 0, (size_t)V * 4 + 16, stream);

    int gv = (V + THREADS - 1) / THREADS;
    int ge = (E + THREADS - 1) / THREADS;

    precompute_kernel<<<gv, THREADS, 0, stream>>>(x, w_self0, w_n00, w_n10,
                                                  w_self11, w_n01, w_n11,
                                                  table, selfbuf, V);
    histogram_kernel<<<ge, THREADS, 0, stream>>>(dst, count, rank, E);
    alloc_kernel<<<gv, THREADS, 0, stream>>>(count, off, cursor, V);
    edge_kernel<<<ge, THREADS, 0, stream>>>(src, dst, angles, transporters,
                                            table, off, rank, msg, E);
    reduce_finalize_kernel<<<gv, THREADS, 0, stream>>>(msg, off, count,
                                                       selfbuf, e1, e2, out, V);
}

// Round 3
// 258.235 us; speedup vs baseline: 1.6490x; 1.0166x over previous
//
#include <hip/hip_runtime.h>
#include <math.h>

// EquivariantWSSHead: V=100000 vertices, E=1600000 edges, C0=C1=16.
//
// R1: 4 fp global atomics/edge -> 321us edge kernel (32B write-through per
//     atomic, ~24G atomics/s ceiling).
// R2: 1 int global atomic/edge (histogram) -> still 67us for that kernel
//     alone; per-atomic cost is constant. Conclusion: any O(E) global-atomic
//     design is floored near ~70us. Scattered 16B msg stores also RMW whole
//     lines.
// R3: ZERO global atomics. Bucket = 128 consecutive dst vertices (NB=782).
//     K2 count:   per-(block,bin) LDS histogram -> count matrix (no atomics)
//     K3a/K3b:    exact exclusive offsets (column scan + bin scan)
//     K4 scatter: place (src,dstlow,ang,tr) int4 into disjoint sub-ranges
//                 (LDS cursor atomics only); writes are contiguous runs
//     K5 bucket:  one block per bucket, LDS fp accumulators (ds_add_f32),
//                 gather 64B table line per edge, finalize fused
//
// Per-edge math factors through per-source-vertex dot products:
//   u1·w = cg*(a·w) - sg*(b·w),  u2·w = sg*(a·w) + cg*(b·w)
// so K1 precomputes a 16-float (64 B) table per vertex; each edge gathers
// exactly one cache line.

#define THREADS 256
#define VB 128           // vertices per bucket
#define VB_SHIFT 7
#define NBLK 128         // blocks for count/scatter passes
#define MAXNB 1024       // NB = ceil(V/128) <= 1024 for V <= 131072

__global__ void precompute_kernel(const float* __restrict__ x,
                                  const float* __restrict__ w_self0,
                                  const float* __restrict__ w_n00,
                                  const float* __restrict__ w_n10,
                                  const float* __restrict__ w_self11,
                                  const float* __restrict__ w_n01,
                                  const float* __restrict__ w_n11,
                                  float* __restrict__ table,
                                  float* __restrict__ selfbuf,
                                  int V) {
    int v = blockIdx.x * blockDim.x + threadIdx.x;
    if (v >= V) return;
    const float* xr = x + (size_t)v * 48;
    float x0[16], a[16], b[16];
#pragma unroll
    for (int i = 0; i < 16; ++i) x0[i] = xr[i];
#pragma unroll
    for (int i = 0; i < 16; ++i) { a[i] = xr[16 + 2 * i]; b[i] = xr[17 + 2 * i]; }

    float d00 = 0.f, aw0 = 0.f, bw0 = 0.f, aw1 = 0.f, bw1 = 0.f;
    float d01a = 0.f, d01b = 0.f;
    float aP = 0.f, bP = 0.f, aQ = 0.f, bQ = 0.f;
    float aR = 0.f, bR = 0.f, aS = 0.f, bS = 0.f;
    float selfmag = 0.f, t1s = 0.f, t2s = 0.f;
#pragma unroll
    for (int i = 0; i < 16; ++i) {
        d00     += x0[i] * w_n00[i];
        selfmag += x0[i] * w_self0[i];
        d01a    += x0[i] * w_n01[i * 2 + 0];
        d01b    += x0[i] * w_n01[i * 2 + 1];
        float w0 = w_n10[i * 2 + 0], w1 = w_n10[i * 2 + 1];
        aw0 += a[i] * w0;  bw0 += b[i] * w0;
        aw1 += a[i] * w1;  bw1 += b[i] * w1;
        float p = w_n11[i * 4 + 0], q = w_n11[i * 4 + 1];
        float r = w_n11[i * 4 + 2], s = w_n11[i * 4 + 3];
        aP += a[i] * p;  bP += b[i] * p;
        aQ += a[i] * q;  bQ += b[i] * q;
        aR += a[i] * r;  bR += b[i] * r;
        aS += a[i] * s;  bS += b[i] * s;
        float sa_ = w_self11[i * 2 + 0], sb_ = w_self11[i * 2 + 1];
        t1s += a[i] * sa_ - b[i] * sb_;
        t2s += b[i] * sa_ + a[i] * sb_;
    }
    float* t = table + (size_t)v * 16;
    t[0] = d00;  t[1] = aw0;  t[2] = bw0;  t[3] = aw1;
    t[4] = bw1;  t[5] = d01a; t[6] = d01b; t[7] = aP;
    t[8] = bP;   t[9] = aQ;   t[10] = bQ;  t[11] = aR;
    t[12] = bR;  t[13] = aS;  t[14] = bS;  t[15] = 0.f;
    float* sf = selfbuf + (size_t)v * 4;
    sf[0] = selfmag; sf[1] = t1s; sf[2] = t2s; sf[3] = 0.f;
}

// K2: per-(block,bin) histogram. No global atomics.
__global__ void count_kernel(const int* __restrict__ dst,
                             int* __restrict__ cntmat,
                             int E, int chunk, int NB, int NBpad) {
    __shared__ int hist[MAXNB];
    for (int i = threadIdx.x; i < NB; i += blockDim.x) hist[i] = 0;
    __syncthreads();
    int b = blockIdx.x;
    int lo = b * chunk;
    int hi = min(E, lo + chunk);
    for (int e = lo + threadIdx.x; e < hi; e += blockDim.x)
        atomicAdd(&hist[dst[e] >> VB_SHIFT], 1);
    __syncthreads();
    for (int i = threadIdx.x; i < NB; i += blockDim.x)
        cntmat[(size_t)b * NBpad + i] = hist[i];
}

// K3a: exclusive scan down each bin's column (over blocks); in-place.
__global__ void colscan_kernel(int* __restrict__ cntmat,
                               int* __restrict__ total,
                               int nblk, int NB, int NBpad) {
    int bin = blockIdx.x * blockDim.x + threadIdx.x;
    if (bin >= NB) return;
    int run = 0;
    for (int b = 0; b < nblk; ++b) {
        int c = cntmat[(size_t)b * NBpad + bin];
        cntmat[(size_t)b * NBpad + bin] = run;
        run += c;
    }
    total[bin] = run;
}

// K3b: exclusive scan over bin totals -> bucket_base. One block, 1024 thr.
__global__ void binscan_kernel(const int* __restrict__ total,
                               int* __restrict__ bucket_base,
                               int NB) {
    __shared__ int s[1024];
    int tid = threadIdx.x;
    int t = (tid < NB) ? total[tid] : 0;
    s[tid] = t;
    __syncthreads();
    for (int d = 1; d < 1024; d <<= 1) {
        int u = (tid >= d) ? s[tid - d] : 0;
        __syncthreads();
        s[tid] += u;
        __syncthreads();
    }
    if (tid < NB) bucket_base[tid] = s[tid] - t;
}

// K4: place each edge's payload into its bucket's region. LDS cursors only.
__global__ void scatter_kernel(const int* __restrict__ src,
                               const int* __restrict__ dst,
                               const float* __restrict__ angles,
                               const float* __restrict__ transporters,
                               const int* __restrict__ cntmat,
                               const int* __restrict__ bucket_base,
                               int4* __restrict__ payload,
                               int E, int chunk, int NB, int NBpad) {
    __shared__ int cursor[MAXNB];
    int b = blockIdx.x;
    for (int i = threadIdx.x; i < NB; i += blockDim.x)
        cursor[i] = bucket_base[i] + cntmat[(size_t)b * NBpad + i];
    __syncthreads();
    int lo = b * chunk;
    int hi = min(E, lo + chunk);
    for (int e = lo + threadIdx.x; e < hi; e += blockDim.x) {
        int d = dst[e];
        int bin = d >> VB_SHIFT;
        int pos = atomicAdd(&cursor[bin], 1);
        payload[pos] = make_int4(src[e], d & (VB - 1),
                                 __float_as_int(angles[e]),
                                 __float_as_int(transporters[e]));
    }
}

// K5: one block per bucket. LDS fp accumulators + fused finalize.
__global__ void bucket_kernel(const int4* __restrict__ payload,
                              const int* __restrict__ bucket_base,
                              const int* __restrict__ total,
                              const float* __restrict__ table,
                              const float* __restrict__ selfbuf,
                              const float* __restrict__ e1,
                              const float* __restrict__ e2,
                              float* __restrict__ out,
                              int V) {
    __shared__ float acc[VB * 4];
    for (int i = threadIdx.x; i < VB * 4; i += blockDim.x) acc[i] = 0.f;
    __syncthreads();
    int bkt = blockIdx.x;
    int base = bucket_base[bkt];
    int n = total[bkt];
    for (int k = threadIdx.x; k < n; k += blockDim.x) {
        int4 pl = payload[base + k];
        int s = pl.x, dl = pl.y;
        float ang = __int_as_float(pl.z), trv = __int_as_float(pl.w);
        float st, ct, sg, cg;
        sincosf(ang, &st, &ct);
        sincosf(trv, &sg, &cg);
        float c2t = ct * ct - st * st;
        float s2t = 2.0f * st * ct;

        const float4* tp = (const float4*)(table + (size_t)s * 16);
        float4 T0 = tp[0], T1 = tp[1], T2 = tp[2], T3 = tp[3];
        float d00 = T0.x, aw0 = T0.y, bw0 = T0.z, aw1 = T0.w;
        float bw1 = T1.x, d01a = T1.y, d01b = T1.z, aP = T1.w;
        float bP = T2.x, aQ = T2.y, bQ = T2.z, aR = T2.w;
        float bR = T3.x, aS = T3.y, bS = T3.z;

        float u1w0 = cg * aw0 - sg * bw0, u2w0 = sg * aw0 + cg * bw0;
        float u1w1 = cg * aw1 - sg * bw1, u2w1 = sg * aw1 + cg * bw1;
        float m0 = d00 + ct * u1w0 + st * u2w0 - st * u1w1 + ct * u2w1;

        float u1p = cg * aP - sg * bP, u2p = sg * aP + cg * bP;
        float u1q = cg * aQ - sg * bQ, u2q = sg * aQ + cg * bQ;
        float u1r = cg * aR - sg * bR, u2r = sg * aR + cg * bR;
        float u1s = cg * aS - sg * bS, u2s = sg * aS + cg * bS;

        float mv1 = d01a * ct - d01b * st
                  + u1p - u2q
                  + c2t * u1r + s2t * u2r
                  - (s2t * u1s - c2t * u2s);
        float mv2 = d01a * st + d01b * ct
                  + u2p + u1q
                  + s2t * u1r - c2t * u2r
                  + c2t * u1s + s2t * u2s;

        atomicAdd(&acc[dl * 4 + 0], m0);
        atomicAdd(&acc[dl * 4 + 1], mv1);
        atomicAdd(&acc[dl * 4 + 2], mv2);
        atomicAdd(&acc[dl * 4 + 3], 1.0f);
    }
    __syncthreads();
    int t = threadIdx.x;
    if (t < VB) {
        int v = bkt * VB + t;
        if (v < V) {
            float inv = 1.0f / fmaxf(acc[t * 4 + 3], 1.0f);
            const float* sf = selfbuf + (size_t)v * 4;
            float mag = acc[t * 4 + 0] * inv + sf[0];
            float t1  = acc[t * 4 + 1] * inv + sf[1];
            float t2  = acc[t * 4 + 2] * inv + sf[2];
            float scale = 2.0f / (1.0f + expf(-mag));
            float e1x = e1[v * 3 + 0], e1y = e1[v * 3 + 1], e1z = e1[v * 3 + 2];
            float e2x = e2[v * 3 + 0], e2y = e2[v * 3 + 1], e2z = e2[v * 3 + 2];
            out[v * 3 + 0] = (t1 * e1x + t2 * e2x) * scale;
            out[v * 3 + 1] = (t1 * e1y + t2 * e2y) * scale;
            out[v * 3 + 2] = (t1 * e1z + t2 * e2z) * scale;
        }
    }
}

extern "C" void kernel_launch(void* const* d_in, const int* in_sizes, int n_in,
                              void* d_out, int out_size, void* d_ws, size_t ws_size,
                              hipStream_t stream) {
    const float* x            = (const float*)d_in[0];
    const int*   edge_index   = (const int*)d_in[1];
    const float* angles       = (const float*)d_in[2];
    const float* transporters = (const float*)d_in[3];
    const float* e1           = (const float*)d_in[4];
    const float* e2           = (const float*)d_in[5];
    const float* w_self0      = (const float*)d_in[6];
    const float* w_n00        = (const float*)d_in[7];
    const float* w_n10        = (const float*)d_in[8];
    const float* w_self11     = (const float*)d_in[9];
    const float* w_n01        = (const float*)d_in[10];
    const float* w_n11        = (const float*)d_in[11];
    float* out = (float*)d_out;

    int V = in_sizes[0] / 48;
    int E = in_sizes[2];
    const int* src = edge_index;
    const int* dst = edge_index + E;

    int NB = (V + VB - 1) / VB;          // 782 for V=100000
    int NBpad = (NB + 3) & ~3;
    int chunk = (E + NBLK - 1) / NBLK;

    char* p = (char*)d_ws;
    int* cntmat      = (int*)p;  p += (size_t)NBLK * NBpad * 4;
    int* total       = (int*)p;  p += (size_t)NBpad * 4;
    int* bucket_base = (int*)p;  p += (size_t)NBpad * 4;
    p = (char*)(((uintptr_t)p + 15) & ~(uintptr_t)15);
    float* table   = (float*)p;  p += (size_t)V * 16 * 4;
    float* selfbuf = (float*)p;  p += (size_t)V * 4 * 4;
    p = (char*)(((uintptr_t)p + 15) & ~(uintptr_t)15);
    int4* payload  = (int4*)p;   // E * 16 bytes

    int gv = (V + THREADS - 1) / THREADS;

    precompute_kernel<<<gv, THREADS, 0, stream>>>(x, w_self0, w_n00, w_n10,
                                                  w_self11, w_n01, w_n11,
                                                  table, selfbuf, V);
    count_kernel<<<NBLK, THREADS, 0, stream>>>(dst, cntmat, E, chunk, NB, NBpad);
    colscan_kernel<<<(NB + THREADS - 1) / THREADS, THREADS, 0, stream>>>(
        cntmat, total, NBLK, NB, NBpad);
    binscan_kernel<<<1, 1024, 0, stream>>>(total, bucket_base, NB);
    scatter_kernel<<<NBLK, THREADS, 0, stream>>>(src, dst, angles, transporters,
                                                 cntmat, bucket_base, payload,
                                                 E, chunk, NB, NBpad);
    bucket_kernel<<<NB, THREADS, 0, stream>>>(payload, bucket_base, total,
                                              table, selfbuf, e1, e2, out, V);
}

// Round 4
// 201.591 us; speedup vs baseline: 2.1123x; 1.2810x over previous
//
#include <hip/hip_runtime.h>
#include <math.h>

// EquivariantWSSHead: V=100000 vertices, E=1600000 edges, C0=C1=16.
//
// R1: 4 fp global atomics/edge -> 321us (32B write-through/atomic).
// R2: 1 int global atomic/edge -> 67us histogram; ~24G atomics/s ceiling.
// R3: zero-global-atomic bucket binning, but NBLK=128 blocks -> 4.8%
//     occupancy; scatter 63us, serial colscan/binscan tails. 258us.
// R4: same binning, fixed shapes:
//     - count/scatter: 256 blocks x 1024 threads (1 block/CU)
//     - bin-major cntmat + wave-per-bin int4 column scan
//     - FIXED capacity S per bucket (8.5-sigma margin) -> no binscan
//     - message math fused into scatter (payload = m0,mv1,mv2,dl);
//       bucket kernel is a pure sequential reduce + finalize
//     - zero global atomics, zero memsets, 5 launches
//
// Per-edge math factors through per-source-vertex dot products:
//   u1·w = cg*(a·w) - sg*(b·w),  u2·w = sg*(a·w) + cg*(b·w)
// so precompute makes a 16-float (64B) table per vertex; each edge gathers
// exactly one cache line (L2/LLC-resident, 6.4MB).

#define VB 128           // vertices per bucket
#define VB_SHIFT 7
#define NBLK 256         // blocks for count/scatter passes (1 per CU)
#define BIGT 1024        // threads for count/scatter
#define MAXNB 1024       // NB = ceil(V/128) <= 1024 for V <= 131072

__global__ void precompute_kernel(const float* __restrict__ x,
                                  const float* __restrict__ w_self0,
                                  const float* __restrict__ w_n00,
                                  const float* __restrict__ w_n10,
                                  const float* __restrict__ w_self11,
                                  const float* __restrict__ w_n01,
                                  const float* __restrict__ w_n11,
                                  float* __restrict__ table,
                                  float* __restrict__ selfbuf,
                                  int V) {
    int v = blockIdx.x * blockDim.x + threadIdx.x;
    if (v >= V) return;
    const float* xr = x + (size_t)v * 48;
    float x0[16], a[16], b[16];
#pragma unroll
    for (int i = 0; i < 16; ++i) x0[i] = xr[i];
#pragma unroll
    for (int i = 0; i < 16; ++i) { a[i] = xr[16 + 2 * i]; b[i] = xr[17 + 2 * i]; }

    float d00 = 0.f, aw0 = 0.f, bw0 = 0.f, aw1 = 0.f, bw1 = 0.f;
    float d01a = 0.f, d01b = 0.f;
    float aP = 0.f, bP = 0.f, aQ = 0.f, bQ = 0.f;
    float aR = 0.f, bR = 0.f, aS = 0.f, bS = 0.f;
    float selfmag = 0.f, t1s = 0.f, t2s = 0.f;
#pragma unroll
    for (int i = 0; i < 16; ++i) {
        d00     += x0[i] * w_n00[i];
        selfmag += x0[i] * w_self0[i];
        d01a    += x0[i] * w_n01[i * 2 + 0];
        d01b    += x0[i] * w_n01[i * 2 + 1];
        float w0 = w_n10[i * 2 + 0], w1 = w_n10[i * 2 + 1];
        aw0 += a[i] * w0;  bw0 += b[i] * w0;
        aw1 += a[i] * w1;  bw1 += b[i] * w1;
        float p = w_n11[i * 4 + 0], q = w_n11[i * 4 + 1];
        float r = w_n11[i * 4 + 2], s = w_n11[i * 4 + 3];
        aP += a[i] * p;  bP += b[i] * p;
        aQ += a[i] * q;  bQ += b[i] * q;
        aR += a[i] * r;  bR += b[i] * r;
        aS += a[i] * s;  bS += b[i] * s;
        float sa_ = w_self11[i * 2 + 0], sb_ = w_self11[i * 2 + 1];
        t1s += a[i] * sa_ - b[i] * sb_;
        t2s += b[i] * sa_ + a[i] * sb_;
    }
    float* t = table + (size_t)v * 16;
    t[0] = d00;  t[1] = aw0;  t[2] = bw0;  t[3] = aw1;
    t[4] = bw1;  t[5] = d01a; t[6] = d01b; t[7] = aP;
    t[8] = bP;   t[9] = aQ;   t[10] = bQ;  t[11] = aR;
    t[12] = bR;  t[13] = aS;  t[14] = bS;  t[15] = 0.f;
    float* sf = selfbuf + (size_t)v * 4;
    sf[0] = selfmag; sf[1] = t1s; sf[2] = t2s; sf[3] = 0.f;
}

// K2: per-(block,bin) histogram, bin-major output. No global atomics.
__global__ __launch_bounds__(BIGT)
void count_kernel(const int* __restrict__ dst,
                  int* __restrict__ cntmat,   // [NB][NBLK]
                  int E, int chunk, int NB) {
    __shared__ int hist[MAXNB];
    for (int i = threadIdx.x; i < NB; i += blockDim.x) hist[i] = 0;
    __syncthreads();
    int b = blockIdx.x;
    int lo = b * chunk;
    int hi = min(E, lo + chunk);
    for (int e = lo + threadIdx.x; e < hi; e += blockDim.x)
        atomicAdd(&hist[dst[e] >> VB_SHIFT], 1);
    __syncthreads();
    for (int i = threadIdx.x; i < NB; i += blockDim.x)
        cntmat[(size_t)i * NBLK + b] = hist[i];
}

// K3: one wave per bin; int4 inclusive->exclusive scan over the 256-entry
// column (contiguous in bin-major layout). total[bin] = bucket fill count.
__global__ void colscan_kernel(int* __restrict__ cntmat,
                               int* __restrict__ total,
                               int NB) {
    int lane = threadIdx.x & 63;
    int wv = threadIdx.x >> 6;
    int bin = blockIdx.x * 4 + wv;
    if (bin >= NB) return;
    int4 c = *(int4*)&cntmat[(size_t)bin * NBLK + lane * 4];
    int s0 = c.x, s1 = s0 + c.y, s2 = s1 + c.z, s3 = s2 + c.w;
    int incl = s3;
#pragma unroll
    for (int d = 1; d < 64; d <<= 1) {
        int n = __shfl_up(incl, d);
        if (lane >= d) incl += n;
    }
    int ex = incl - s3;   // exclusive prefix of this lane's 4-sum
    int4 o;
    o.x = ex; o.y = ex + s0; o.z = ex + s1; o.w = ex + s2;
    *(int4*)&cntmat[(size_t)bin * NBLK + lane * 4] = o;
    if (lane == 63) total[bin] = incl;
}

// K4: fused message-compute + binned scatter. LDS cursor atomics only.
// payload[bin*S + offset] = (m0, mv1, mv2, dl-bits)
__global__ __launch_bounds__(BIGT)
void scatter_compute_kernel(const int* __restrict__ src,
                            const int* __restrict__ dst,
                            const float* __restrict__ angles,
                            const float* __restrict__ transporters,
                            const float* __restrict__ table,
                            const int* __restrict__ cntmat,
                            float4* __restrict__ payload,
                            int E, int chunk, int NB, int S) {
    __shared__ int cursor[MAXNB];
    int b = blockIdx.x;
    for (int i = threadIdx.x; i < NB; i += blockDim.x)
        cursor[i] = i * S + cntmat[(size_t)i * NBLK + b];
    __syncthreads();
    int lo = b * chunk;
    int hi = min(E, lo + chunk);
    for (int e = lo + threadIdx.x; e < hi; e += blockDim.x) {
        int d = dst[e];
        int bin = d >> VB_SHIFT;
        int dl = d & (VB - 1);
        int s = src[e];
        float ang = angles[e], trv = transporters[e];
        float st, ct, sg, cg;
        sincosf(ang, &st, &ct);
        sincosf(trv, &sg, &cg);
        float c2t = ct * ct - st * st;
        float s2t = 2.0f * st * ct;

        const float4* tp = (const float4*)(table + (size_t)s * 16);
        float4 T0 = tp[0], T1 = tp[1], T2 = tp[2], T3 = tp[3];
        float d00 = T0.x, aw0 = T0.y, bw0 = T0.z, aw1 = T0.w;
        float bw1 = T1.x, d01a = T1.y, d01b = T1.z, aP = T1.w;
        float bP = T2.x, aQ = T2.y, bQ = T2.z, aR = T2.w;
        float bR = T3.x, aS = T3.y, bS = T3.z;

        float u1w0 = cg * aw0 - sg * bw0, u2w0 = sg * aw0 + cg * bw0;
        float u1w1 = cg * aw1 - sg * bw1, u2w1 = sg * aw1 + cg * bw1;
        float m0 = d00 + ct * u1w0 + st * u2w0 - st * u1w1 + ct * u2w1;

        float u1p = cg * aP - sg * bP, u2p = sg * aP + cg * bP;
        float u1q = cg * aQ - sg * bQ, u2q = sg * aQ + cg * bQ;
        float u1r = cg * aR - sg * bR, u2r = sg * aR + cg * bR;
        float u1s = cg * aS - sg * bS, u2s = sg * aS + cg * bS;

        float mv1 = d01a * ct - d01b * st
                  + u1p - u2q
                  + c2t * u1r + s2t * u2r
                  - (s2t * u1s - c2t * u2s);
        float mv2 = d01a * st + d01b * ct
                  + u2p + u1q
                  + s2t * u1r - c2t * u2r
                  + c2t * u1s + s2t * u2s;

        int pos = atomicAdd(&cursor[bin], 1);
        payload[pos] = make_float4(m0, mv1, mv2, __int_as_float(dl));
    }
}

// K5: one block per bucket: sequential payload read, LDS fp accumulate,
// fused finalize.
__global__ void bucket_kernel(const float4* __restrict__ payload,
                              const int* __restrict__ total,
                              const float* __restrict__ selfbuf,
                              const float* __restrict__ e1,
                              const float* __restrict__ e2,
                              float* __restrict__ out,
                              int V, int S) {
    __shared__ float acc[VB * 4];
    for (int i = threadIdx.x; i < VB * 4; i += blockDim.x) acc[i] = 0.f;
    __syncthreads();
    int bkt = blockIdx.x;
    int base = bkt * S;
    int n = total[bkt];
    for (int k = threadIdx.x; k < n; k += blockDim.x) {
        float4 m = payload[base + k];
        int dl = __float_as_int(m.w);
        atomicAdd(&acc[dl * 4 + 0], m.x);
        atomicAdd(&acc[dl * 4 + 1], m.y);
        atomicAdd(&acc[dl * 4 + 2], m.z);
        atomicAdd(&acc[dl * 4 + 3], 1.0f);
    }
    __syncthreads();
    int t = threadIdx.x;
    if (t < VB) {
        int v = bkt * VB + t;
        if (v < V) {
            float inv = 1.0f / fmaxf(acc[t * 4 + 3], 1.0f);
            const float* sf = selfbuf + (size_t)v * 4;
            float mag = acc[t * 4 + 0] * inv + sf[0];
            float t1  = acc[t * 4 + 1] * inv + sf[1];
            float t2  = acc[t * 4 + 2] * inv + sf[2];
            float scale = 2.0f / (1.0f + expf(-mag));
            float e1x = e1[v * 3 + 0], e1y = e1[v * 3 + 1], e1z = e1[v * 3 + 2];
            float e2x = e2[v * 3 + 0], e2y = e2[v * 3 + 1], e2z = e2[v * 3 + 2];
            out[v * 3 + 0] = (t1 * e1x + t2 * e2x) * scale;
            out[v * 3 + 1] = (t1 * e1y + t2 * e2y) * scale;
            out[v * 3 + 2] = (t1 * e1z + t2 * e2z) * scale;
        }
    }
}

extern "C" void kernel_launch(void* const* d_in, const int* in_sizes, int n_in,
                              void* d_out, int out_size, void* d_ws, size_t ws_size,
                              hipStream_t stream) {
    const float* x            = (const float*)d_in[0];
    const int*   edge_index   = (const int*)d_in[1];
    const float* angles       = (const float*)d_in[2];
    const float* transporters = (const float*)d_in[3];
    const float* e1           = (const float*)d_in[4];
    const float* e2           = (const float*)d_in[5];
    const float* w_self0      = (const float*)d_in[6];
    const float* w_n00        = (const float*)d_in[7];
    const float* w_n10        = (const float*)d_in[8];
    const float* w_self11     = (const float*)d_in[9];
    const float* w_n01        = (const float*)d_in[10];
    const float* w_n11        = (const float*)d_in[11];
    float* out = (float*)d_out;

    int V = in_sizes[0] / 48;
    int E = in_sizes[2];
    const int* src = edge_index;
    const int* dst = edge_index + E;

    int NB = (V + VB - 1) / VB;          // 782 for V=100000
    int chunk = (E + NBLK - 1) / NBLK;   // 6250
    // fixed per-bucket capacity: mean + mean/8 + 128 (~8.5 sigma for this E/NB)
    int avg = E / NB;
    int S = (avg + (avg >> 3) + 128 + 3) & ~3;   // 2432 for E=1.6M

    char* p = (char*)d_ws;
    int* cntmat = (int*)p;  p += (size_t)NB * NBLK * 4;   // bin-major
    int* total  = (int*)p;  p += (size_t)((NB + 3) & ~3) * 4;
    float* table   = (float*)p;  p += (size_t)V * 16 * 4;
    float* selfbuf = (float*)p;  p += (size_t)V * 4 * 4;
    p = (char*)(((uintptr_t)p + 15) & ~(uintptr_t)15);
    float4* payload = (float4*)p;   // NB * S * 16 bytes (~30.4 MB)

    int gv = (V + 255) / 256;

    precompute_kernel<<<gv, 256, 0, stream>>>(x, w_self0, w_n00, w_n10,
                                              w_self11, w_n01, w_n11,
                                              table, selfbuf, V);
    count_kernel<<<NBLK, BIGT, 0, stream>>>(dst, cntmat, E, chunk, NB);
    colscan_kernel<<<(NB + 3) / 4, 256, 0, stream>>>(cntmat, total, NB);
    scatter_compute_kernel<<<NBLK, BIGT, 0, stream>>>(src, dst, angles,
                                                      transporters, table,
                                                      cntmat, payload,
                                                      E, chunk, NB, S);
    bucket_kernel<<<NB, 256, 0, stream>>>(payload, total, selfbuf,
                                          e1, e2, out, V, S);
}

// Round 7
// 199.006 us; speedup vs baseline: 2.1398x; 1.0130x over previous
//
#include <hip/hip_runtime.h>
#include <math.h>

// EquivariantWSSHead: V=100000 vertices, E=1600000 edges, C0=C1=16.
//
// R1: 4 fp global atomics/edge -> 321us (32B write-through/atomic).
// R2: 1 int global atomic/edge -> 67us; ~24G atomics/s ceiling.
// R3: zero-global-atomic binning, 128 blocks -> 4.8% occupancy. 258us.
// R4: 256x1024 shapes, fused compute-in-scatter. 202us; scatter is
//     traffic-bound: FETCH 85.5MB (fp32 table 6.4MB > 4MB per-XCD L2,
//     gathers miss; payload 16B stores write-allocate) at 2.3TB/s.
// R5/R6: shrink working set + payload. R5 source killed the container
//     twice (suspect ext_vector_type kernel params + nontemporal
//     builtins); R6 = same algorithm with plain uint2 + normal ld/st:
//     - table bf16-packed: 32B/vertex -> 3.2MB, L2-resident gathers
//     - payload 8B: (bf16 m0, bf16 mv1, bf16 mv2, u16 dl)
//     - bucket: per-wave LDS acc replication (no same-addr atomic serial)
//
// Per-edge math factors through per-source-vertex dot products:
//   u1·w = cg*(a·w) - sg*(b·w),  u2·w = sg*(a·w) + cg*(b·w)
// so precompute makes a 16-bf16 (32B) table line per vertex; each edge
// gathers exactly one half-line.

#define VB 128           // vertices per bucket
#define VB_SHIFT 7
#define NBLK 256         // blocks for count/scatter passes (1 per CU)
#define BIGT 1024        // threads for count/scatter
#define MAXNB 1024       // NB = ceil(V/128) <= 1024 for V <= 131072

typedef unsigned int uint32;

static __device__ __forceinline__ uint32 f2bf(float f) {
    uint32 u = __float_as_uint(f);
    return (u + 0x7FFFu + ((u >> 16) & 1u)) >> 16;   // RNE to bf16
}
static __device__ __forceinline__ uint32 pack2(float lo, float hi) {
    return f2bf(lo) | (f2bf(hi) << 16);
}
static __device__ __forceinline__ float bf_lo(uint32 u) {
    return __uint_as_float(u << 16);
}
static __device__ __forceinline__ float bf_hi(uint32 u) {
    return __uint_as_float(u & 0xFFFF0000u);
}

__global__ void precompute_kernel(const float* __restrict__ x,
                                  const float* __restrict__ w_self0,
                                  const float* __restrict__ w_n00,
                                  const float* __restrict__ w_n10,
                                  const float* __restrict__ w_self11,
                                  const float* __restrict__ w_n01,
                                  const float* __restrict__ w_n11,
                                  uint32* __restrict__ table,   // 8 u32/vertex
                                  float* __restrict__ selfbuf,
                                  int V) {
    int v = blockIdx.x * blockDim.x + threadIdx.x;
    if (v >= V) return;
    const float* xr = x + (size_t)v * 48;
    float x0[16], a[16], b[16];
#pragma unroll
    for (int i = 0; i < 16; ++i) x0[i] = xr[i];
#pragma unroll
    for (int i = 0; i < 16; ++i) { a[i] = xr[16 + 2 * i]; b[i] = xr[17 + 2 * i]; }

    float d00 = 0.f, aw0 = 0.f, bw0 = 0.f, aw1 = 0.f, bw1 = 0.f;
    float d01a = 0.f, d01b = 0.f;
    float aP = 0.f, bP = 0.f, aQ = 0.f, bQ = 0.f;
    float aR = 0.f, bR = 0.f, aS = 0.f, bS = 0.f;
    float selfmag = 0.f, t1s = 0.f, t2s = 0.f;
#pragma unroll
    for (int i = 0; i < 16; ++i) {
        d00     += x0[i] * w_n00[i];
        selfmag += x0[i] * w_self0[i];
        d01a    += x0[i] * w_n01[i * 2 + 0];
        d01b    += x0[i] * w_n01[i * 2 + 1];
        float w0 = w_n10[i * 2 + 0], w1 = w_n10[i * 2 + 1];
        aw0 += a[i] * w0;  bw0 += b[i] * w0;
        aw1 += a[i] * w1;  bw1 += b[i] * w1;
        float p = w_n11[i * 4 + 0], q = w_n11[i * 4 + 1];
        float r = w_n11[i * 4 + 2], s = w_n11[i * 4 + 3];
        aP += a[i] * p;  bP += b[i] * p;
        aQ += a[i] * q;  bQ += b[i] * q;
        aR += a[i] * r;  bR += b[i] * r;
        aS += a[i] * s;  bS += b[i] * s;
        float sa_ = w_self11[i * 2 + 0], sb_ = w_self11[i * 2 + 1];
        t1s += a[i] * sa_ - b[i] * sb_;
        t2s += b[i] * sa_ + a[i] * sb_;
    }
    uint4 w0, w1;
    w0.x = pack2(d00, aw0);  w0.y = pack2(bw0, aw1);
    w0.z = pack2(bw1, d01a); w0.w = pack2(d01b, aP);
    w1.x = pack2(bP, aQ);    w1.y = pack2(bQ, aR);
    w1.z = pack2(bR, aS);    w1.w = pack2(bS, 0.f);
    uint4* tp = (uint4*)(table + (size_t)v * 8);
    tp[0] = w0;  tp[1] = w1;
    float* sf = selfbuf + (size_t)v * 4;
    sf[0] = selfmag; sf[1] = t1s; sf[2] = t2s; sf[3] = 0.f;
}

// K2: per-(block,bin) histogram, bin-major output. No global atomics.
__global__ __launch_bounds__(BIGT)
void count_kernel(const int* __restrict__ dst,
                  int* __restrict__ cntmat,   // [NB][NBLK]
                  int E, int chunk, int NB) {
    __shared__ int hist[MAXNB];
    for (int i = threadIdx.x; i < NB; i += blockDim.x) hist[i] = 0;
    __syncthreads();
    int b = blockIdx.x;
    int lo = b * chunk;
    int hi = min(E, lo + chunk);
    for (int e = lo + threadIdx.x; e < hi; e += blockDim.x)
        atomicAdd(&hist[dst[e] >> VB_SHIFT], 1);
    __syncthreads();
    for (int i = threadIdx.x; i < NB; i += blockDim.x)
        cntmat[(size_t)i * NBLK + b] = hist[i];
}

// K3: one wave per bin; int4 scan over the 256-entry column.
__global__ void colscan_kernel(int* __restrict__ cntmat,
                               int* __restrict__ total,
                               int NB) {
    int lane = threadIdx.x & 63;
    int wv = threadIdx.x >> 6;
    int bin = blockIdx.x * 4 + wv;
    if (bin >= NB) return;
    int4 c = *(int4*)&cntmat[(size_t)bin * NBLK + lane * 4];
    int s0 = c.x, s1 = s0 + c.y, s2 = s1 + c.z, s3 = s2 + c.w;
    int incl = s3;
#pragma unroll
    for (int d = 1; d < 64; d <<= 1) {
        int n = __shfl_up(incl, d);
        if (lane >= d) incl += n;
    }
    int ex = incl - s3;
    int4 o;
    o.x = ex; o.y = ex + s0; o.z = ex + s1; o.w = ex + s2;
    *(int4*)&cntmat[(size_t)bin * NBLK + lane * 4] = o;
    if (lane == 63) total[bin] = incl;
}

// K4: fused message-compute + binned scatter. LDS cursor atomics only.
// payload entry (8B): .x = bf16(m0) | bf16(mv1)<<16
//                     .y = bf16(mv2) | dl<<16
__global__ __launch_bounds__(BIGT)
void scatter_compute_kernel(const int* __restrict__ src,
                            const int* __restrict__ dst,
                            const float* __restrict__ angles,
                            const float* __restrict__ transporters,
                            const uint32* __restrict__ table,
                            const int* __restrict__ cntmat,
                            uint2* __restrict__ payload,
                            int E, int chunk, int NB, int S) {
    __shared__ int cursor[MAXNB];
    int b = blockIdx.x;
    for (int i = threadIdx.x; i < NB; i += blockDim.x)
        cursor[i] = i * S + cntmat[(size_t)i * NBLK + b];
    __syncthreads();
    int lo = b * chunk;
    int hi = min(E, lo + chunk);
    for (int e = lo + threadIdx.x; e < hi; e += blockDim.x) {
        int d = dst[e];
        int bin = d >> VB_SHIFT;
        int dl = d & (VB - 1);
        int s = src[e];
        float ang = angles[e], trv = transporters[e];
        float st, ct, sg, cg;
        sincosf(ang, &st, &ct);
        sincosf(trv, &sg, &cg);
        float c2t = ct * ct - st * st;
        float s2t = 2.0f * st * ct;

        const uint4* tp = (const uint4*)(table + (size_t)s * 8);
        uint4 W0 = tp[0], W1 = tp[1];
        float d00 = bf_lo(W0.x), aw0 = bf_hi(W0.x);
        float bw0 = bf_lo(W0.y), aw1 = bf_hi(W0.y);
        float bw1 = bf_lo(W0.z), d01a = bf_hi(W0.z);
        float d01b = bf_lo(W0.w), aP = bf_hi(W0.w);
        float bP = bf_lo(W1.x), aQ = bf_hi(W1.x);
        float bQ = bf_lo(W1.y), aR = bf_hi(W1.y);
        float bR = bf_lo(W1.z), aS = bf_hi(W1.z);
        float bS = bf_lo(W1.w);

        float u1w0 = cg * aw0 - sg * bw0, u2w0 = sg * aw0 + cg * bw0;
        float u1w1 = cg * aw1 - sg * bw1, u2w1 = sg * aw1 + cg * bw1;
        float m0 = d00 + ct * u1w0 + st * u2w0 - st * u1w1 + ct * u2w1;

        float u1p = cg * aP - sg * bP, u2p = sg * aP + cg * bP;
        float u1q = cg * aQ - sg * bQ, u2q = sg * aQ + cg * bQ;
        float u1r = cg * aR - sg * bR, u2r = sg * aR + cg * bR;
        float u1s = cg * aS - sg * bS, u2s = sg * aS + cg * bS;

        float mv1 = d01a * ct - d01b * st
                  + u1p - u2q
                  + c2t * u1r + s2t * u2r
                  - (s2t * u1s - c2t * u2s);
        float mv2 = d01a * st + d01b * ct
                  + u2p + u1q
                  + s2t * u1r - c2t * u2r
                  + c2t * u1s + s2t * u2s;

        int pos = atomicAdd(&cursor[bin], 1);
        uint2 pl;
        pl.x = pack2(m0, mv1);
        pl.y = f2bf(mv2) | ((uint32)dl << 16);
        payload[pos] = pl;
    }
}

// K5: one block per bucket; per-wave replicated LDS accumulators.
__global__ void bucket_kernel(const uint2* __restrict__ payload,
                              const int* __restrict__ total,
                              const float* __restrict__ selfbuf,
                              const float* __restrict__ e1,
                              const float* __restrict__ e2,
                              float* __restrict__ out,
                              int V, int S) {
    __shared__ float acc[4][VB * 4];   // one copy per wave
    for (int i = threadIdx.x; i < 4 * VB * 4; i += blockDim.x)
        ((float*)acc)[i] = 0.f;
    __syncthreads();
    int wv = threadIdx.x >> 6;
    int bkt = blockIdx.x;
    int base = bkt * S;
    int n = total[bkt];
    float* myacc = acc[wv];
    for (int k = threadIdx.x; k < n; k += blockDim.x) {
        uint2 pl = payload[base + k];
        float m0  = bf_lo(pl.x);
        float mv1 = bf_hi(pl.x);
        float mv2 = bf_lo(pl.y);
        int dl = pl.y >> 16;
        atomicAdd(&myacc[dl * 4 + 0], m0);
        atomicAdd(&myacc[dl * 4 + 1], mv1);
        atomicAdd(&myacc[dl * 4 + 2], mv2);
        atomicAdd(&myacc[dl * 4 + 3], 1.0f);
    }
    __syncthreads();
    int t = threadIdx.x;
    if (t < VB) {
        int v = bkt * VB + t;
        if (v < V) {
            float A0 = acc[0][t * 4 + 0] + acc[1][t * 4 + 0]
                     + acc[2][t * 4 + 0] + acc[3][t * 4 + 0];
            float A1 = acc[0][t * 4 + 1] + acc[1][t * 4 + 1]
                     + acc[2][t * 4 + 1] + acc[3][t * 4 + 1];
            float A2 = acc[0][t * 4 + 2] + acc[1][t * 4 + 2]
                     + acc[2][t * 4 + 2] + acc[3][t * 4 + 2];
            float A3 = acc[0][t * 4 + 3] + acc[1][t * 4 + 3]
                     + acc[2][t * 4 + 3] + acc[3][t * 4 + 3];
            float inv = 1.0f / fmaxf(A3, 1.0f);
            const float* sf = selfbuf + (size_t)v * 4;
            float mag = A0 * inv + sf[0];
            float t1  = A1 * inv + sf[1];
            float t2  = A2 * inv + sf[2];
            float scale = 2.0f / (1.0f + expf(-mag));
            float e1x = e1[v * 3 + 0], e1y = e1[v * 3 + 1], e1z = e1[v * 3 + 2];
            float e2x = e2[v * 3 + 0], e2y = e2[v * 3 + 1], e2z = e2[v * 3 + 2];
            out[v * 3 + 0] = (t1 * e1x + t2 * e2x) * scale;
            out[v * 3 + 1] = (t1 * e1y + t2 * e2y) * scale;
            out[v * 3 + 2] = (t1 * e1z + t2 * e2z) * scale;
        }
    }
}

extern "C" void kernel_launch(void* const* d_in, const int* in_sizes, int n_in,
                              void* d_out, int out_size, void* d_ws, size_t ws_size,
                              hipStream_t stream) {
    const float* x            = (const float*)d_in[0];
    const int*   edge_index   = (const int*)d_in[1];
    const float* angles       = (const float*)d_in[2];
    const float* transporters = (const float*)d_in[3];
    const float* e1           = (const float*)d_in[4];
    const float* e2           = (const float*)d_in[5];
    const float* w_self0      = (const float*)d_in[6];
    const float* w_n00        = (const float*)d_in[7];
    const float* w_n10        = (const float*)d_in[8];
    const float* w_self11     = (const float*)d_in[9];
    const float* w_n01        = (const float*)d_in[10];
    const float* w_n11        = (const float*)d_in[11];
    float* out = (float*)d_out;

    int V = in_sizes[0] / 48;
    int E = in_sizes[2];
    const int* src = edge_index;
    const int* dst = edge_index + E;

    int NB = (V + VB - 1) / VB;          // 782 for V=100000
    int chunk = (E + NBLK - 1) / NBLK;   // 6250
    int avg = E / NB;
    int S = (avg + (avg >> 3) + 128 + 7) & ~7;   // ~8.5 sigma margin

    char* p = (char*)d_ws;
    int* cntmat = (int*)p;  p += (size_t)NB * NBLK * 4;   // bin-major
    int* total  = (int*)p;  p += (size_t)((NB + 3) & ~3) * 4;
    uint32* table  = (uint32*)p;  p += (size_t)V * 8 * 4;   // bf16-packed
    float* selfbuf = (float*)p;   p += (size_t)V * 4 * 4;
    p = (char*)(((uintptr_t)p + 15) & ~(uintptr_t)15);
    uint2* payload = (uint2*)p;   // NB * S * 8 bytes (~15 MB)

    int gv = (V + 255) / 256;

    precompute_kernel<<<gv, 256, 0, stream>>>(x, w_self0, w_n00, w_n10,
                                              w_self11, w_n01, w_n11,
                                              table, selfbuf, V);
    count_kernel<<<NBLK, BIGT, 0, stream>>>(dst, cntmat, E, chunk, NB);
    colscan_kernel<<<(NB + 3) / 4, 256, 0, stream>>>(cntmat, total, NB);
    scatter_compute_kernel<<<NBLK, BIGT, 0, stream>>>(src, dst, angles,
                                                      transporters, table,
                                                      cntmat, payload,
                                                      E, chunk, NB, S);
    bucket_kernel<<<NB, 256, 0, stream>>>(payload, total, selfbuf,
                                          e1, e2, out, V, S);
}

// Round 9
// 183.474 us; speedup vs baseline: 2.3209x; 1.0847x over previous
//
#include <hip/hip_runtime.h>
#include <math.h>

// EquivariantWSSHead: V=100000 vertices, E=1600000 edges, C0=C1=16.
//
// R1: 4 fp global atomics/edge -> 321us (32B write-through/atomic).
// R2: 1 int global atomic/edge -> 67us; ~24G atomics/s ceiling.
// R3: zero-global-atomic binning, 128 blocks -> 4.8% occupancy. 258us.
// R4: 256x1024 shapes, fused compute-in-scatter. 202us.
// R5/R6: ext_vector/nontemporal constructs killed the container; uint2 ok.
// R7: bf16 table+payload. 199us; scatter WRITE 41MB vs 12.8MB payload ->
//     cross-XCD false sharing on bin-major partial lines; ~146us in the
//     other 4 launches.
// R8: fused count+scan+compute+scatter w/ 57KB LDS payload stage ->
//     container died twice; can't identify crasher by inspection.
// R9: same fusion, NO giant LDS stage (bisect): block-private payload
//     regions alone kill the false sharing (one writer per line; L2 is
//     writeback so 8B stores merge into full lines). pass1 histograms dst
//     (chunk re-read is L1-hot), LDS scan -> runmat column, pass2 does
//     message math + direct store via LDS cursors. LDS = 8KB. 3 launches.
//
// Per-edge math factors through per-source-vertex dot products:
//   u1.w = cg*(a.w) - sg*(b.w),  u2.w = sg*(a.w) + cg*(b.w)
// so precompute makes a 16-bf16 (32B) table line per vertex; each edge
// gathers exactly one half-line (3.2MB table, L2/LLC-resident).

#define VB 128           // vertices per bucket
#define VB_SHIFT 7
#define BIGT 1024        // threads for scatter_all
#define MAXNB 1024       // NB = ceil(V/128) <= 1024 for V <= 131072
#define CHUNK 6250       // edges per scatter block
#define CHUNKP 6272      // padded entries (8B each) -> 64B-aligned regions

typedef unsigned int uint32;

static __device__ __forceinline__ uint32 f2bf(float f) {
    uint32 u = __float_as_uint(f);
    return (u + 0x7FFFu + ((u >> 16) & 1u)) >> 16;   // RNE to bf16
}
static __device__ __forceinline__ uint32 pack2(float lo, float hi) {
    return f2bf(lo) | (f2bf(hi) << 16);
}
static __device__ __forceinline__ float bf_lo(uint32 u) {
    return __uint_as_float(u << 16);
}
static __device__ __forceinline__ float bf_hi(uint32 u) {
    return __uint_as_float(u & 0xFFFF0000u);
}

__global__ void precompute_kernel(const float* __restrict__ x,
                                  const float* __restrict__ w_self0,
                                  const float* __restrict__ w_n00,
                                  const float* __restrict__ w_n10,
                                  const float* __restrict__ w_self11,
                                  const float* __restrict__ w_n01,
                                  const float* __restrict__ w_n11,
                                  uint32* __restrict__ table,   // 8 u32/vertex
                                  float* __restrict__ selfbuf,
                                  int V) {
    int v = blockIdx.x * blockDim.x + threadIdx.x;
    if (v >= V) return;
    const float* xr = x + (size_t)v * 48;
    float x0[16], a[16], b[16];
#pragma unroll
    for (int i = 0; i < 16; ++i) x0[i] = xr[i];
#pragma unroll
    for (int i = 0; i < 16; ++i) { a[i] = xr[16 + 2 * i]; b[i] = xr[17 + 2 * i]; }

    float d00 = 0.f, aw0 = 0.f, bw0 = 0.f, aw1 = 0.f, bw1 = 0.f;
    float d01a = 0.f, d01b = 0.f;
    float aP = 0.f, bP = 0.f, aQ = 0.f, bQ = 0.f;
    float aR = 0.f, bR = 0.f, aS = 0.f, bS = 0.f;
    float selfmag = 0.f, t1s = 0.f, t2s = 0.f;
#pragma unroll
    for (int i = 0; i < 16; ++i) {
        d00     += x0[i] * w_n00[i];
        selfmag += x0[i] * w_self0[i];
        d01a    += x0[i] * w_n01[i * 2 + 0];
        d01b    += x0[i] * w_n01[i * 2 + 1];
        float w0 = w_n10[i * 2 + 0], w1 = w_n10[i * 2 + 1];
        aw0 += a[i] * w0;  bw0 += b[i] * w0;
        aw1 += a[i] * w1;  bw1 += b[i] * w1;
        float p = w_n11[i * 4 + 0], q = w_n11[i * 4 + 1];
        float r = w_n11[i * 4 + 2], s = w_n11[i * 4 + 3];
        aP += a[i] * p;  bP += b[i] * p;
        aQ += a[i] * q;  bQ += b[i] * q;
        aR += a[i] * r;  bR += b[i] * r;
        aS += a[i] * s;  bS += b[i] * s;
        float sa_ = w_self11[i * 2 + 0], sb_ = w_self11[i * 2 + 1];
        t1s += a[i] * sa_ - b[i] * sb_;
        t2s += b[i] * sa_ + a[i] * sb_;
    }
    uint4 w0, w1;
    w0.x = pack2(d00, aw0);  w0.y = pack2(bw0, aw1);
    w0.z = pack2(bw1, d01a); w0.w = pack2(d01b, aP);
    w1.x = pack2(bP, aQ);    w1.y = pack2(bQ, aR);
    w1.z = pack2(bR, aS);    w1.w = pack2(bS, 0.f);
    uint4* tp = (uint4*)(table + (size_t)v * 8);
    tp[0] = w0;  tp[1] = w1;
    float* sf = selfbuf + (size_t)v * 4;
    sf[0] = selfmag; sf[1] = t1s; sf[2] = t2s; sf[3] = 0.f;
}

// K2: fused histogram + scan + message-compute + block-private scatter.
// runmat has NB+1 rows x nblk cols: row i col b = global start index of
// (block b, bin i)'s run in payload; row NB = end of block b's region.
__global__ __launch_bounds__(BIGT)
void scatter_all_kernel(const int* __restrict__ src,
                        const int* __restrict__ dst,
                        const float* __restrict__ angles,
                        const float* __restrict__ transporters,
                        const uint32* __restrict__ table,
                        int* __restrict__ runmat,
                        uint2* __restrict__ payload,
                        int E, int NB, int nblk) {
    __shared__ int cnt_l[MAXNB];
    __shared__ int off_l[MAXNB];

    int b = blockIdx.x;
    int lo = b * CHUNK;
    int hi = min(E, lo + CHUNK);
    int nloc = hi - lo;

    for (int i = threadIdx.x; i < NB; i += BIGT) cnt_l[i] = 0;
    __syncthreads();

    // pass1: histogram this block's dst chunk (25KB, stays L1/L2-hot)
    for (int e = lo + threadIdx.x; e < hi; e += BIGT)
        atomicAdd(&cnt_l[dst[e] >> VB_SHIFT], 1);
    __syncthreads();

    // inclusive scan of cnt_l into off_l (Hillis-Steele, NB <= 1024)
    if (threadIdx.x < NB) off_l[threadIdx.x] = cnt_l[threadIdx.x];
    __syncthreads();
    for (int stp = 1; stp < NB; stp <<= 1) {
        int vv = 0;
        if (threadIdx.x < NB && threadIdx.x >= stp)
            vv = off_l[threadIdx.x - stp];
        __syncthreads();
        if (threadIdx.x < NB) off_l[threadIdx.x] += vv;
        __syncthreads();
    }

    // write runmat column b; cnt_l becomes global-index cursors
    int bCH = b * CHUNKP;
    if (threadIdx.x < NB) {
        int ex = off_l[threadIdx.x] - cnt_l[threadIdx.x];
        runmat[(size_t)threadIdx.x * nblk + b] = bCH + ex;
        cnt_l[threadIdx.x] = bCH + ex;
    }
    if (threadIdx.x == 0)
        runmat[(size_t)NB * nblk + b] = bCH + nloc;
    __syncthreads();

    // pass2: message math + direct store into block-private region
    for (int e = lo + threadIdx.x; e < hi; e += BIGT) {
        int d = dst[e];
        int bin = d >> VB_SHIFT;
        int dl = d & (VB - 1);
        int s = src[e];
        float ang = angles[e], trv = transporters[e];
        float st, ct, sg, cg;
        sincosf(ang, &st, &ct);
        sincosf(trv, &sg, &cg);
        float c2t = ct * ct - st * st;
        float s2t = 2.0f * st * ct;

        const uint4* tp = (const uint4*)(table + (size_t)s * 8);
        uint4 W0 = tp[0], W1 = tp[1];
        float d00 = bf_lo(W0.x), aw0 = bf_hi(W0.x);
        float bw0 = bf_lo(W0.y), aw1 = bf_hi(W0.y);
        float bw1 = bf_lo(W0.z), d01a = bf_hi(W0.z);
        float d01b = bf_lo(W0.w), aP = bf_hi(W0.w);
        float bP = bf_lo(W1.x), aQ = bf_hi(W1.x);
        float bQ = bf_lo(W1.y), aR = bf_hi(W1.y);
        float bR = bf_lo(W1.z), aS = bf_hi(W1.z);
        float bS = bf_lo(W1.w);

        float u1w0 = cg * aw0 - sg * bw0, u2w0 = sg * aw0 + cg * bw0;
        float u1w1 = cg * aw1 - sg * bw1, u2w1 = sg * aw1 + cg * bw1;
        float m0 = d00 + ct * u1w0 + st * u2w0 - st * u1w1 + ct * u2w1;

        float u1p = cg * aP - sg * bP, u2p = sg * aP + cg * bP;
        float u1q = cg * aQ - sg * bQ, u2q = sg * aQ + cg * bQ;
        float u1r = cg * aR - sg * bR, u2r = sg * aR + cg * bR;
        float u1s = cg * aS - sg * bS, u2s = sg * aS + cg * bS;

        float mv1 = d01a * ct - d01b * st
                  + u1p - u2q
                  + c2t * u1r + s2t * u2r
                  - (s2t * u1s - c2t * u2s);
        float mv2 = d01a * st + d01b * ct
                  + u2p + u1q
                  + s2t * u1r - c2t * u2r
                  + c2t * u1s + s2t * u2s;

        int pos = atomicAdd(&cnt_l[bin], 1);
        uint2 pl;
        pl.x = pack2(m0, mv1);
        pl.y = f2bf(mv2) | ((uint32)dl << 16);
        payload[pos] = pl;
    }
}

// K3: one block per bucket; thread t walks scatter-block t's run.
__global__ void bucket_kernel(const uint2* __restrict__ payload,
                              const int* __restrict__ runmat,
                              const float* __restrict__ selfbuf,
                              const float* __restrict__ e1,
                              const float* __restrict__ e2,
                              float* __restrict__ out,
                              int V, int NB, int nblk) {
    __shared__ float acc[4][VB * 4];   // one copy per wave
    for (int i = threadIdx.x; i < 4 * VB * 4; i += blockDim.x)
        ((float*)acc)[i] = 0.f;
    __syncthreads();
    int bin = blockIdx.x;
    int wv = threadIdx.x >> 6;
    float* myacc = acc[wv];
    for (int b = threadIdx.x; b < nblk; b += blockDim.x) {
        int st = runmat[(size_t)bin * nblk + b];
        int en = runmat[(size_t)(bin + 1) * nblk + b];
        for (int k = st; k < en; ++k) {
            uint2 pl = payload[k];
            float m0  = bf_lo(pl.x);
            float mv1 = bf_hi(pl.x);
            float mv2 = bf_lo(pl.y);
            int dl = pl.y >> 16;
            atomicAdd(&myacc[dl * 4 + 0], m0);
            atomicAdd(&myacc[dl * 4 + 1], mv1);
            atomicAdd(&myacc[dl * 4 + 2], mv2);
            atomicAdd(&myacc[dl * 4 + 3], 1.0f);
        }
    }
    __syncthreads();
    int t = threadIdx.x;
    if (t < VB) {
        int v = bin * VB + t;
        if (v < V) {
            float A0 = acc[0][t * 4 + 0] + acc[1][t * 4 + 0]
                     + acc[2][t * 4 + 0] + acc[3][t * 4 + 0];
            float A1 = acc[0][t * 4 + 1] + acc[1][t * 4 + 1]
                     + acc[2][t * 4 + 1] + acc[3][t * 4 + 1];
            float A2 = acc[0][t * 4 + 2] + acc[1][t * 4 + 2]
                     + acc[2][t * 4 + 2] + acc[3][t * 4 + 2];
            float A3 = acc[0][t * 4 + 3] + acc[1][t * 4 + 3]
                     + acc[2][t * 4 + 3] + acc[3][t * 4 + 3];
            float inv = 1.0f / fmaxf(A3, 1.0f);
            const float* sf = selfbuf + (size_t)v * 4;
            float mag = A0 * inv + sf[0];
            float t1  = A1 * inv + sf[1];
            float t2  = A2 * inv + sf[2];
            float scale = 2.0f / (1.0f + expf(-mag));
            float e1x = e1[v * 3 + 0], e1y = e1[v * 3 + 1], e1z = e1[v * 3 + 2];
            float e2x = e2[v * 3 + 0], e2y = e2[v * 3 + 1], e2z = e2[v * 3 + 2];
            out[v * 3 + 0] = (t1 * e1x + t2 * e2x) * scale;
            out[v * 3 + 1] = (t1 * e1y + t2 * e2y) * scale;
            out[v * 3 + 2] = (t1 * e1z + t2 * e2z) * scale;
        }
    }
}

extern "C" void kernel_launch(void* const* d_in, const int* in_sizes, int n_in,
                              void* d_out, int out_size, void* d_ws, size_t ws_size,
                              hipStream_t stream) {
    const float* x            = (const float*)d_in[0];
    const int*   edge_index   = (const int*)d_in[1];
    const float* angles       = (const float*)d_in[2];
    const float* transporters = (const float*)d_in[3];
    const float* e1           = (const float*)d_in[4];
    const float* e2           = (const float*)d_in[5];
    const float* w_self0      = (const float*)d_in[6];
    const float* w_n00        = (const float*)d_in[7];
    const float* w_n10        = (const float*)d_in[8];
    const float* w_self11     = (const float*)d_in[9];
    const float* w_n01        = (const float*)d_in[10];
    const float* w_n11        = (const float*)d_in[11];
    float* out = (float*)d_out;

    int V = in_sizes[0] / 48;
    int E = in_sizes[2];
    const int* src = edge_index;
    const int* dst = edge_index + E;

    int NB = (V + VB - 1) / VB;          // 782 for V=100000
    int nblk = (E + CHUNK - 1) / CHUNK;  // 256 for E=1.6M

    char* p = (char*)d_ws;
    int* runmat = (int*)p;  p += (size_t)(NB + 1) * nblk * 4;   // ~0.8MB
    uint32* table  = (uint32*)p;  p += (size_t)V * 8 * 4;       // bf16-packed
    float* selfbuf = (float*)p;   p += (size_t)V * 4 * 4;
    p = (char*)(((uintptr_t)p + 63) & ~(uintptr_t)63);
    uint2* payload = (uint2*)p;   // nblk * CHUNKP * 8 bytes (~12.9 MB)

    int gv = (V + 255) / 256;

    precompute_kernel<<<gv, 256, 0, stream>>>(x, w_self0, w_n00, w_n10,
                                              w_self11, w_n01, w_n11,
                                              table, selfbuf, V);
    scatter_all_kernel<<<nblk, BIGT, 0, stream>>>(src, dst, angles,
                                                  transporters, table,
                                                  runmat, payload,
                                                  E, NB, nblk);
    bucket_kernel<<<NB, 256, 0, stream>>>(payload, runmat, selfbuf,
                                          e1, e2, out, V, NB, nblk);
}